// Round 2
// baseline (410.390 us; speedup 1.0000x reference)
//
#include <hip/hip_runtime.h>
#include <hip/hip_bf16.h>

#define BATCH 32
#define CDIM  256
#define TDIM  4096

using short8  = __attribute__((ext_vector_type(8))) short;
using floatx4 = __attribute__((ext_vector_type(4))) float;

// RNE float -> bf16 (finite inputs), manual to avoid non-trivially-copyable
// __hip_bfloat162 in __builtin_bit_cast.
__device__ __forceinline__ unsigned f2bf(float f) {
  unsigned u = __float_as_uint(f);
  return (u + 0x7fffu + ((u >> 16) & 1u)) >> 16;
}
__device__ __forceinline__ unsigned cvt_pk_bf16(float a, float b) {
  return f2bf(a) | (f2bf(b) << 16);
}
__device__ __forceinline__ float bf_lo(unsigned u) { return __uint_as_float(u << 16); }
__device__ __forceinline__ float bf_hi(unsigned u) { return __uint_as_float(u & 0xffff0000u); }

// ---------------------------------------------------------------------------
// Kernel 1: per-batch Gram with split-bf16.
//   E1 = h·h^T, E2 = l·h^T   (energy[i,j] = E1[i,j] + E2[i,j] + E2[j,i])
// Tile: 64(I) x 64(J), K = 4096, BK = 32. Grid = 32 batches * 4*4 tiles = 512.
// 256 threads = 4 waves in 2x2, wave tile 32x32 (2x2 of 16x16x32 MFMA).
// ---------------------------------------------------------------------------
__global__ __launch_bounds__(256, 2)
void gram_kernel(const float* __restrict__ x,
                 float* __restrict__ E1, float* __restrict__ E2) {
  // LDS: 64 rows x 32 bf16, row stride 40 shorts (80 B) for bank spread.
  __shared__ __align__(16) short hI[64 * 40];
  __shared__ __align__(16) short lI[64 * 40];
  __shared__ __align__(16) short hJ[64 * 40];

  const int tid = threadIdx.x;
  const int bx  = blockIdx.x;
  const int b   = bx >> 4;
  const int i0  = ((bx >> 2) & 3) * 64;
  const int j0  = (bx & 3) * 64;

  const float* xb = x + ((size_t)b << 20);   // b * 256 * 4096

  // staging map: 4 threads per row, 8 fp32 each
  const int srow = tid >> 2;
  const int skq  = (tid & 3) << 3;
  const float* pI = xb + (size_t)(i0 + srow) * TDIM + skq;
  const float* pJ = xb + (size_t)(j0 + srow) * TDIM + skq;

  floatx4 acc_hh[2][2], acc_lh[2][2];
#pragma unroll
  for (int m = 0; m < 2; ++m)
#pragma unroll
    for (int n = 0; n < 2; ++n) {
      acc_hh[m][n] = {0.f, 0.f, 0.f, 0.f};
      acc_lh[m][n] = {0.f, 0.f, 0.f, 0.f};
    }

  const int lane = tid & 63;
  const int w    = tid >> 6;
  const int wm   = (w >> 1) << 5;   // 0 / 32
  const int wn   = (w & 1) << 5;    // 0 / 32
  const int fr   = lane & 15;
  const int q    = lane >> 4;

  const int aoff0 = (wm + fr) * 40 + q * 8;
  const int aoff1 = aoff0 + 16 * 40;
  const int boff0 = (wn + fr) * 40 + q * 8;
  const int boff1 = boff0 + 16 * 40;

  // prefetch step 0
  float4 rI0 = *(const float4*)pI;
  float4 rI1 = *(const float4*)(pI + 4);
  float4 rJ0 = *(const float4*)pJ;
  float4 rJ1 = *(const float4*)(pJ + 4);

  for (int ks = 0; ks < TDIM / 32; ++ks) {
    // convert current regs (h = bf16 RNE, l = bf16(x - h))
    unsigned hi01 = cvt_pk_bf16(rI0.x, rI0.y), hi23 = cvt_pk_bf16(rI0.z, rI0.w);
    unsigned hi45 = cvt_pk_bf16(rI1.x, rI1.y), hi67 = cvt_pk_bf16(rI1.z, rI1.w);
    unsigned li01 = cvt_pk_bf16(rI0.x - bf_lo(hi01), rI0.y - bf_hi(hi01));
    unsigned li23 = cvt_pk_bf16(rI0.z - bf_lo(hi23), rI0.w - bf_hi(hi23));
    unsigned li45 = cvt_pk_bf16(rI1.x - bf_lo(hi45), rI1.y - bf_hi(hi45));
    unsigned li67 = cvt_pk_bf16(rI1.z - bf_lo(hi67), rI1.w - bf_hi(hi67));
    unsigned hj01 = cvt_pk_bf16(rJ0.x, rJ0.y), hj23 = cvt_pk_bf16(rJ0.z, rJ0.w);
    unsigned hj45 = cvt_pk_bf16(rJ1.x, rJ1.y), hj67 = cvt_pk_bf16(rJ1.z, rJ1.w);

    __syncthreads();   // previous iteration's LDS reads done
    *(uint4*)(&hI[srow * 40 + skq]) = make_uint4(hi01, hi23, hi45, hi67);
    *(uint4*)(&lI[srow * 40 + skq]) = make_uint4(li01, li23, li45, li67);
    *(uint4*)(&hJ[srow * 40 + skq]) = make_uint4(hj01, hj23, hj45, hj67);
    __syncthreads();

    if (ks < TDIM / 32 - 1) {
      pI += 32; pJ += 32;
      rI0 = *(const float4*)pI; rI1 = *(const float4*)(pI + 4);
      rJ0 = *(const float4*)pJ; rJ1 = *(const float4*)(pJ + 4);
    }

    short8 Ah0 = *(const short8*)(&hI[aoff0]);
    short8 Ah1 = *(const short8*)(&hI[aoff1]);
    short8 Al0 = *(const short8*)(&lI[aoff0]);
    short8 Al1 = *(const short8*)(&lI[aoff1]);
    short8 Bh0 = *(const short8*)(&hJ[boff0]);
    short8 Bh1 = *(const short8*)(&hJ[boff1]);

    acc_hh[0][0] = __builtin_amdgcn_mfma_f32_16x16x32_bf16(Ah0, Bh0, acc_hh[0][0], 0, 0, 0);
    acc_hh[0][1] = __builtin_amdgcn_mfma_f32_16x16x32_bf16(Ah0, Bh1, acc_hh[0][1], 0, 0, 0);
    acc_hh[1][0] = __builtin_amdgcn_mfma_f32_16x16x32_bf16(Ah1, Bh0, acc_hh[1][0], 0, 0, 0);
    acc_hh[1][1] = __builtin_amdgcn_mfma_f32_16x16x32_bf16(Ah1, Bh1, acc_hh[1][1], 0, 0, 0);
    acc_lh[0][0] = __builtin_amdgcn_mfma_f32_16x16x32_bf16(Al0, Bh0, acc_lh[0][0], 0, 0, 0);
    acc_lh[0][1] = __builtin_amdgcn_mfma_f32_16x16x32_bf16(Al0, Bh1, acc_lh[0][1], 0, 0, 0);
    acc_lh[1][0] = __builtin_amdgcn_mfma_f32_16x16x32_bf16(Al1, Bh0, acc_lh[1][0], 0, 0, 0);
    acc_lh[1][1] = __builtin_amdgcn_mfma_f32_16x16x32_bf16(Al1, Bh1, acc_lh[1][1], 0, 0, 0);
  }

  // epilogue: C/D layout col = lane&15, row = (lane>>4)*4 + reg
#pragma unroll
  for (int m = 0; m < 2; ++m)
#pragma unroll
    for (int n = 0; n < 2; ++n) {
      const int gr = i0 + wm + 16 * m + 4 * q;
      const int gc = j0 + wn + 16 * n + fr;
      size_t base = (((size_t)b * CDIM + gr) << 8) + gc;
#pragma unroll
      for (int r = 0; r < 4; ++r) {
        E1[base + ((size_t)r << 8)] = acc_hh[m][n][r];
        E2[base + ((size_t)r << 8)] = acc_lh[m][n][r];
      }
    }
}

// ---------------------------------------------------------------------------
// Kernel 2: softmax over rows of energy = E1 + E2 + E2^T, att = softmax(-energy)
// one block (256 thr) per (b, i) row
// ---------------------------------------------------------------------------
__global__ __launch_bounds__(256)
void softmax_kernel(const float* __restrict__ E1, const float* __restrict__ E2,
                    __hip_bfloat16* __restrict__ att) {
  const int b = blockIdx.x >> 8;
  const int i = blockIdx.x & 255;
  const int j = threadIdx.x;
  const size_t base = (size_t)b << 16;

  float e = E1[base + (i << 8) + j] + E2[base + (i << 8) + j] + E2[base + (j << 8) + i];
  float z = -e;

  float m = z;
#pragma unroll
  for (int off = 32; off > 0; off >>= 1) m = fmaxf(m, __shfl_xor(m, off, 64));

  __shared__ float red[8];
  const int wv = j >> 6, ln = j & 63;
  if (ln == 0) red[wv] = m;
  __syncthreads();
  m = fmaxf(fmaxf(red[0], red[1]), fmaxf(red[2], red[3]));

  float p = expf(z - m);
  float s = p;
#pragma unroll
  for (int off = 32; off > 0; off >>= 1) s += __shfl_xor(s, off, 64);
  if (ln == 0) red[4 + wv] = s;
  __syncthreads();
  s = (red[4] + red[5]) + (red[6] + red[7]);

  att[base + (i << 8) + j] = __float2bfloat16(p / s);
}

// ---------------------------------------------------------------------------
// Kernel 3: out = gamma * (att @ x) + x
// Tile 128(M) x 128(N), K = 256, BK = 32. Grid = 32 * 2 * 32 = 2048.
// 4 waves in 2x2, wave tile 64x64 (4x4 of 16x16x32 MFMA).
// ---------------------------------------------------------------------------
__global__ __launch_bounds__(256, 2)
void pv_kernel(const float* __restrict__ x, const __hip_bfloat16* __restrict__ att,
               const float* __restrict__ gamma, float* __restrict__ out) {
  __shared__ __align__(16) short As[128 * 40];   // att rows [i][j], j-contig
  __shared__ __align__(16) short Bt[128 * 40];   // x tile transposed: [t][k]

  const int tid = threadIdx.x;
  const int bx  = blockIdx.x;
  const int b   = bx >> 6;
  const int i0  = ((bx >> 5) & 1) << 7;  // 0 / 128
  const int t0  = (bx & 31) << 7;        // n-tile * 128

  const float* xb = x + ((size_t)b << 20);
  const unsigned short* attb = (const unsigned short*)att + ((size_t)b << 16);

  // A staging: 2 threads per row, 16 bf16 each
  const int arow = tid >> 1;
  const int aoff = (tid & 1) << 4;
  // B staging: thread (kg, tg) loads x[k0+4kg+kk][t0 + tg + 32*tt]
  const int kg = tid >> 5;
  const int tg = tid & 31;

  floatx4 acc[4][4];
#pragma unroll
  for (int m = 0; m < 4; ++m)
#pragma unroll
    for (int n = 0; n < 4; ++n) acc[m][n] = {0.f, 0.f, 0.f, 0.f};

  const int lane = tid & 63;
  const int w    = tid >> 6;
  const int wm   = (w >> 1) << 6;  // 0 / 64
  const int wn   = (w & 1) << 6;
  const int fr   = lane & 15;
  const int q    = lane >> 4;

  const unsigned short* pA = attb + (size_t)(i0 + arow) * CDIM + aoff;
  const float* pB = xb + (size_t)(kg * 4) * TDIM + t0 + tg;

  uint4 ra0 = *(const uint4*)pA;
  uint4 ra1 = *(const uint4*)(pA + 8);
  float xv[4][4];
#pragma unroll
  for (int kk = 0; kk < 4; ++kk)
#pragma unroll
    for (int tt = 0; tt < 4; ++tt) xv[kk][tt] = pB[kk * TDIM + tt * 32];

  for (int ks = 0; ks < CDIM / 32; ++ks) {
    unsigned bu[4][2];
#pragma unroll
    for (int tt = 0; tt < 4; ++tt) {
      bu[tt][0] = cvt_pk_bf16(xv[0][tt], xv[1][tt]);
      bu[tt][1] = cvt_pk_bf16(xv[2][tt], xv[3][tt]);
    }

    __syncthreads();
    *(uint4*)(&As[arow * 40 + aoff])     = ra0;
    *(uint4*)(&As[arow * 40 + aoff + 8]) = ra1;
#pragma unroll
    for (int tt = 0; tt < 4; ++tt)
      *(uint2*)(&Bt[(tg + tt * 32) * 40 + kg * 4]) = make_uint2(bu[tt][0], bu[tt][1]);
    __syncthreads();

    if (ks < CDIM / 32 - 1) {
      pA += 32; pB += (size_t)32 * TDIM;
      ra0 = *(const uint4*)pA;
      ra1 = *(const uint4*)(pA + 8);
#pragma unroll
      for (int kk = 0; kk < 4; ++kk)
#pragma unroll
        for (int tt = 0; tt < 4; ++tt) xv[kk][tt] = pB[kk * TDIM + tt * 32];
    }

    short8 Af[4], Bf[4];
#pragma unroll
    for (int m = 0; m < 4; ++m) Af[m] = *(const short8*)(&As[(wm + 16 * m + fr) * 40 + q * 8]);
#pragma unroll
    for (int n = 0; n < 4; ++n) Bf[n] = *(const short8*)(&Bt[(wn + 16 * n + fr) * 40 + q * 8]);
#pragma unroll
    for (int m = 0; m < 4; ++m)
#pragma unroll
      for (int n = 0; n < 4; ++n)
        acc[m][n] = __builtin_amdgcn_mfma_f32_16x16x32_bf16(Af[m], Bf[n], acc[m][n], 0, 0, 0);
  }

  const float g = gamma[0];
#pragma unroll
  for (int m = 0; m < 4; ++m)
#pragma unroll
    for (int n = 0; n < 4; ++n) {
      const int gr = i0 + wm + 16 * m + 4 * q;
      const int gc = t0 + wn + 16 * n + fr;
      size_t base = ((size_t)b << 20) + (size_t)gr * TDIM + gc;
#pragma unroll
      for (int r = 0; r < 4; ++r) {
        size_t idx = base + (size_t)r * TDIM;
        out[idx] = g * acc[m][n][r] + x[idx];
      }
    }
}

// ---------------------------------------------------------------------------
extern "C" void kernel_launch(void* const* d_in, const int* in_sizes, int n_in,
                              void* d_out, int out_size, void* d_ws, size_t ws_size,
                              hipStream_t stream) {
  (void)in_sizes; (void)n_in; (void)out_size; (void)ws_size;
  const float* x     = (const float*)d_in[0];
  const float* gamma = (const float*)d_in[1];
  float* out = (float*)d_out;

  const size_t EN = (size_t)BATCH * CDIM * CDIM;  // 2,097,152
  float* E1 = (float*)d_ws;
  float* E2 = E1 + EN;
  __hip_bfloat16* att = (__hip_bfloat16*)(E2 + EN);
  // ws usage: 8 MiB + 8 MiB + 4 MiB = 20 MiB

  gram_kernel<<<dim3(512), dim3(256), 0, stream>>>(x, E1, E2);
  softmax_kernel<<<dim3(BATCH * CDIM), dim3(256), 0, stream>>>(E1, E2, att);
  pv_kernel<<<dim3(2048), dim3(256), 0, stream>>>(x, att, gamma, out);
}